// Round 6
// baseline (270.419 us; speedup 1.0000x reference)
//
#include <hip/hip_runtime.h>
#include <stdint.h>

#define S_LEN  4096
#define HID    1024
#define NHEAD  2
#define HDIM   512
#define NSPLIT 4
#define KS_STRIDE 520   // 512 + 8 pad elems -> bank-floor on QK^T reads
#define LN_EPS 1e-5f

typedef __bf16 bf16x8 __attribute__((ext_vector_type(8)));
typedef float  f32x4  __attribute__((ext_vector_type(4)));

__device__ __forceinline__ float b2f(unsigned short u) {
    return __uint_as_float(((unsigned int)u) << 16);
}
__device__ __forceinline__ unsigned short f2b(float f) {
    unsigned int u = __float_as_uint(f);
    u += 0x7FFFu + ((u >> 16) & 1u);   // round-to-nearest-even
    return (unsigned short)(u >> 16);
}

// async 16B global->LDS (DMA; LDS dest must be wave-uniform base + lane*16)
__device__ __forceinline__ void async_cp16(const void* g, void* l) {
    __builtin_amdgcn_global_load_lds(
        (const __attribute__((address_space(1))) unsigned int*)g,
        (__attribute__((address_space(3))) unsigned int*)l, 16, 0, 0);
}

// -------- fp32->bf16 for 4 weight matrices (z=0..3) + semb (z==4) in one launch --------
__global__ void k_cvt4s(const float* __restrict__ i0, const float* __restrict__ i1,
                        const float* __restrict__ i2, const float* __restrict__ i3,
                        unsigned short* __restrict__ o0, unsigned short* __restrict__ o1,
                        unsigned short* __restrict__ o2, unsigned short* __restrict__ o3,
                        const float* __restrict__ Ws, const float* __restrict__ sd,
                        const float* __restrict__ bs, float* __restrict__ semb) {
    int z = blockIdx.y;
    if (z == 4) {
        int j = blockIdx.x * blockDim.x + threadIdx.x;
        if (j >= HID) return;
        float acc = bs[j];
        const float* row = Ws + j * 64;
        #pragma unroll
        for (int d = 0; d < 64; ++d) acc += row[d] * sd[d];
        semb[j] = acc;
        return;
    }
    const float* in = z == 0 ? i0 : z == 1 ? i1 : z == 2 ? i2 : i3;
    unsigned short* o = z == 0 ? o0 : z == 1 ? o1 : z == 2 ? o2 : o3;
    int i = (blockIdx.x * blockDim.x + threadIdx.x) * 8;
    float4 a = *(const float4*)(in + i);
    float4 b = *(const float4*)(in + i + 4);
    unsigned short r[8] = {f2b(a.x), f2b(a.y), f2b(a.z), f2b(a.w),
                           f2b(b.x), f2b(b.y), f2b(b.z), f2b(b.w)};
    *(uint4*)(o + i) = *(const uint4*)r;
}

// ---------------- Xb = bf16(X);  kv_in = bf16(X + semb) ----------------
__global__ void k_kvin(const float* __restrict__ X,
                       const float* __restrict__ semb,
                       unsigned short* __restrict__ Xb,
                       unsigned short* __restrict__ kv) {
    int idx = (blockIdx.x * blockDim.x + threadIdx.x) * 8;
    if (idx >= S_LEN * HID) return;
    int col = idx & (HID - 1);
    float4 a = *(const float4*)(X + idx);
    float4 b = *(const float4*)(X + idx + 4);
    unsigned short xo[8] = {f2b(a.x), f2b(a.y), f2b(a.z), f2b(a.w),
                            f2b(b.x), f2b(b.y), f2b(b.z), f2b(b.w)};
    *(uint4*)(Xb + idx) = *(const uint4*)xo;
    unsigned short o[8];
    o[0] = f2b(a.x + semb[col + 0]);
    o[1] = f2b(a.y + semb[col + 1]);
    o[2] = f2b(a.z + semb[col + 2]);
    o[3] = f2b(a.w + semb[col + 3]);
    o[4] = f2b(b.x + semb[col + 4]);
    o[5] = f2b(b.y + semb[col + 5]);
    o[6] = f2b(b.z + semb[col + 6]);
    o[7] = f2b(b.w + semb[col + 7]);
    *(uint4*)(kv + idx) = *(const uint4*)o;
}

// ---------------- 128x128 GEMM core: C = A @ B^T, bf16 out ----------------
// R15: single-barrier double-buffered pipeline (R3-proven on flash). Old m97 form staged
// tile t and drained it at the very next barrier (zero overlap, TLP-only hiding). Now:
// barrier -> stage(t+1 -> buf^1) -> MFMA(buf): the DMA has the whole MFMA phase to land.
// LDS 32KB/block -> still 3 blocks/CU at 256 thr. bx is the XCD-swizzled block id.
__device__ __forceinline__
void gemm128(const unsigned short* __restrict__ A,
             const unsigned short* __restrict__ B,
             unsigned short* __restrict__ Cb,
             int bx, int nx, int ldc) {
    __shared__ unsigned short As[2][128 * 32];
    __shared__ unsigned short Bs[2][128 * 32];
    int tid  = threadIdx.x;
    int wave = tid >> 6, lane = tid & 63;
    int quad = lane >> 4, l16 = lane & 15;
    int wm = wave >> 1, wn = wave & 1;
    int m0 = (bx / nx) * 128, n0 = (bx % nx) * 128;

    auto stage = [&](int k0, int b) {
        #pragma unroll
        for (int i = 0; i < 2; ++i) {
            int c = tid + i * 256;   // LDS dest c*16B: wave-uniform base + lane*16 -> DMA-legal
            async_cp16(A + (m0 + (c >> 2)) * HID + k0 + (c & 3) * 8, As[b] + c * 8);
            async_cp16(B + (n0 + (c >> 2)) * HID + k0 + (c & 3) * 8, Bs[b] + c * 8);
        }
    };

    f32x4 zero = {0.f, 0.f, 0.f, 0.f};
    f32x4 acc[4][4];
    #pragma unroll
    for (int i = 0; i < 4; ++i)
        #pragma unroll
        for (int j = 0; j < 4; ++j) acc[i][j] = zero;

    stage(0, 0);
    for (int it = 0; it < HID / 32; ++it) {
        int b = it & 1;
        __syncthreads();   // DMA(it -> b) drained (issuing wave's vmcnt); buf b^1 free
        if (it + 1 < HID / 32) stage((it + 1) * 32, b ^ 1);

        bf16x8 af[4], bfr[4];
        #pragma unroll
        for (int i = 0; i < 4; ++i)
            af[i] = *(const bf16x8*)(As[b] + (wm * 64 + i * 16 + l16) * 32 + quad * 8);
        #pragma unroll
        for (int j = 0; j < 4; ++j)
            bfr[j] = *(const bf16x8*)(Bs[b] + (wn * 64 + j * 16 + l16) * 32 + quad * 8);
        #pragma unroll
        for (int i = 0; i < 4; ++i)
            #pragma unroll
            for (int j = 0; j < 4; ++j)
                acc[i][j] = __builtin_amdgcn_mfma_f32_16x16x32_bf16(af[i], bfr[j], acc[i][j], 0, 0, 0);
    }

    #pragma unroll
    for (int i = 0; i < 4; ++i) {
        int rbase = m0 + wm * 64 + i * 16 + quad * 4;  // C/D row = (lane>>4)*4 + reg
        #pragma unroll
        for (int j = 0; j < 4; ++j) {
            int col = n0 + wn * 64 + j * 16 + l16;     // C/D col = lane&15
            #pragma unroll
            for (int r = 0; r < 4; ++r)
                Cb[(size_t)(rbase + r) * ldc + col] = f2b(acc[i][j][r]);
        }
    }
}

// fused Q/K/V projections: blockIdx.z selects the GEMM (256 blocks each, 768 total = 3/CU).
// XCD swizzle on x (neutral-but-harmless here: all inputs L2-resident — R5 lesson).
__global__ __launch_bounds__(256)
void k_gemm_qkv(const unsigned short* __restrict__ Xb,
                const unsigned short* __restrict__ kvin,
                const unsigned short* __restrict__ Wqb,
                const unsigned short* __restrict__ Wkb,
                const unsigned short* __restrict__ Wvb,
                unsigned short* __restrict__ Qb,
                unsigned short* __restrict__ Kb,
                unsigned short* __restrict__ Vt) {
    int bx = (blockIdx.x & 7) * 32 + (blockIdx.x >> 3);
    int z = blockIdx.z;
    if (z == 0)      gemm128(Xb,   Wqb,  Qb,  bx,  8, HID);
    else if (z == 1) gemm128(kvin, Wkb,  Kb,  bx,  8, HID);
    else             gemm128(Wvb,  kvin, Vt,  bx, 32, S_LEN);   // V^T [HID][S_LEN]
}

// ------- out-projection 64x128 tile, fused split-combine + normalize + residual -------
// R15: single-barrier dbuf pipeline. The A-combine (4x b128 L2 loads + VALU + ds_write)
// for tile t+1 is issued BEFORE compute(t) -> its latency hides under the MFMAs (T14-lite).
__global__ __launch_bounds__(256)
void k_gemm_o(const unsigned short* __restrict__ Opart,
              const float* __restrict__ Lbuf,
              const unsigned short* __restrict__ B,
              float* __restrict__ Cf,
              const float* __restrict__ Xres) {
    __shared__ unsigned short As[2][64 * 32];
    __shared__ unsigned short Bs[2][128 * 32];
    const size_t SH = (size_t)S_LEN * HID;
    int tid  = threadIdx.x;
    int wave = tid >> 6, lane = tid & 63;
    int quad = lane >> 4, l16 = lane & 15;
    int bx = (blockIdx.x & 7) * 64 + (blockIdx.x >> 3);
    int m0 = (bx >> 3) * 64, n0 = (bx & 7) * 128;

    int arow  = m0 + (tid >> 2);        // this thread's A row (fixed across k-loop)
    int acol8 = (tid & 3) * 8;          // col offset within the 32-wide k-tile
    float rinv[NHEAD];
    #pragma unroll
    for (int h = 0; h < NHEAD; ++h) {
        float l = 0.f;
        #pragma unroll
        for (int z = 0; z < NSPLIT; ++z)
            l += Lbuf[(z * NHEAD + h) * S_LEN + arow];
        rinv[h] = 1.f / l;
    }

    auto stageB = [&](int k0, int b) {
        #pragma unroll
        for (int i = 0; i < 2; ++i) {
            int c = tid + i * 256;
            async_cp16(B + (n0 + (c >> 2)) * HID + k0 + (c & 3) * 8, Bs[b] + c * 8);
        }
    };
    auto stageA = [&](int k0, int b) {
        float rv = rinv[k0 >> 9];
        const unsigned short* ap = Opart + (size_t)arow * HID + k0 + acol8;
        float s[8] = {0.f, 0.f, 0.f, 0.f, 0.f, 0.f, 0.f, 0.f};
        #pragma unroll
        for (int z = 0; z < NSPLIT; ++z) {
            uint4 v = *(const uint4*)(ap + z * SH);
            unsigned short us[8];
            *(uint4*)us = v;
            #pragma unroll
            for (int e = 0; e < 8; ++e) s[e] += b2f(us[e]);
        }
        unsigned short o8[8];
        #pragma unroll
        for (int e = 0; e < 8; ++e) o8[e] = f2b(s[e] * rv);
        *(uint4*)(As[b] + tid * 8) = *(const uint4*)o8;
    };

    f32x4 zero = {0.f, 0.f, 0.f, 0.f};
    f32x4 acc[4][2];
    #pragma unroll
    for (int i = 0; i < 4; ++i)
        #pragma unroll
        for (int j = 0; j < 2; ++j) acc[i][j] = zero;

    stageB(0, 0);
    stageA(0, 0);
    for (int it = 0; it < HID / 32; ++it) {
        int b = it & 1;
        __syncthreads();   // DMA + ds_writes for tile it (buf b) complete/visible
        if (it + 1 < HID / 32) {
            stageB((it + 1) * 32, b ^ 1);
            stageA((it + 1) * 32, b ^ 1);
        }
        bf16x8 af[4], bfr[2];
        #pragma unroll
        for (int i = 0; i < 4; ++i)
            af[i] = *(const bf16x8*)(As[b] + (i * 16 + l16) * 32 + quad * 8);
        #pragma unroll
        for (int j = 0; j < 2; ++j)
            bfr[j] = *(const bf16x8*)(Bs[b] + (wave * 32 + j * 16 + l16) * 32 + quad * 8);
        #pragma unroll
        for (int i = 0; i < 4; ++i)
            #pragma unroll
            for (int j = 0; j < 2; ++j)
                acc[i][j] = __builtin_amdgcn_mfma_f32_16x16x32_bf16(af[i], bfr[j], acc[i][j], 0, 0, 0);
    }

    #pragma unroll
    for (int i = 0; i < 4; ++i) {
        int rbase = m0 + i * 16 + quad * 4;
        #pragma unroll
        for (int j = 0; j < 2; ++j) {
            int col = n0 + wave * 32 + j * 16 + l16;
            #pragma unroll
            for (int r = 0; r < 4; ++r) {
                size_t o = (size_t)(rbase + r) * HID + col;
                Cf[o] = acc[i][j][r] + Xres[o];
            }
        }
    }
}

// ---------------- flash attention: 128 queries x one (head, key-split of 1024) ----------------
// R12 structure EXACTLY (proven 107 us): single barrier, PV shifted one iter, vf[4] carry.
// Ps swizzle stays reverted (R4: +20% conflicts — counter is cross-wave contention, not
// intra-instruction aliasing). kf/pf reads are at the b128 bank floor (verified analytically).
__global__ __launch_bounds__(512, 2)
void k_flash(const unsigned short* __restrict__ Q,
             const unsigned short* __restrict__ K,
             const unsigned short* __restrict__ Vt,   // [HID][S_LEN]
             const int* __restrict__ mask,
             unsigned short* __restrict__ Opart,      // [NSPLIT][S_LEN][HID] bf16 unnormalized
             float* __restrict__ Lbuf) {              // [NSPLIT][NHEAD][S_LEN]
    __shared__ unsigned short Ks[2][32 * KS_STRIDE];  // double-buffered [key][hd], padded
    __shared__ __bf16 Ps[2][128][40];                 // double-buffered block-shared P
    int tid  = threadIdx.x;
    int wave = tid >> 6, lane = tid & 63;
    int quad = lane >> 4, l16 = lane & 15;
    int head = blockIdx.x / NSPLIT, split = blockIdx.x % NSPLIT, qtile = blockIdx.y;

    // Q fragments (A-operand: A[m=lane&15][k=quad*8+j]), pinned in registers
    int qrow = qtile * 128 + wave * 16 + l16;
    const unsigned short* qp = Q + qrow * HID + head * HDIM;
    bf16x8 qf[16];
    #pragma unroll
    for (int t = 0; t < 16; ++t) qf[t] = *(const bf16x8*)(qp + t * 32 + quad * 8);

    float lsum[4];
    #pragma unroll
    for (int r = 0; r < 4; ++r) lsum[r] = 0.f;
    f32x4 zero = {0.f, 0.f, 0.f, 0.f};
    f32x4 oacc[8][4];                          // 128 q (8 m-tiles) x 64 hd (4 n-tiles)
    #pragma unroll
    for (int mt = 0; mt < 8; ++mt)
        #pragma unroll
        for (int nt = 0; nt < 4; ++nt) oacc[mt][nt] = zero;

    const float scale = 0.044194173824159216f; // 1/sqrt(512)
    const unsigned short* Kbase = K + head * HDIM;
    // per-lane V pointer; wave's 64-hd slice; frag nt at +nt*16*S_LEN, key-step it at +it*32
    const unsigned short* vptr = Vt + (size_t)(head * HDIM + wave * 64 + l16) * S_LEN
                                    + split * 1024 + quad * 8;

    auto stageK = [&](int kt, int buf) {
        int kb = split * 1024 + kt * 32;
        #pragma unroll
        for (int i = 0; i < 4; ++i) {
            int c = tid + i * 512;
            int row = c >> 6, col = (c & 63) * 8;   // per-wave: row uniform, col = lane*16B
            async_cp16(Kbase + (kb + row) * HID + col, &Ks[buf][row * KS_STRIDE + col]);
        }
    };

    // prologue: stage K-tile 0; preload mask for tile 0
    stageK(0, 0);
    int mk0 = 1, mk1 = 1;
    if (head == 0) {
        mk0 = mask[split * 1024 + l16];
        mk1 = mask[split * 1024 + 16 + l16];
    }

    bf16x8 vf[4];
    for (int it = 0; it < 32; ++it) {
        int cur = it & 1;
        __syncthreads();   // Ks[cur] DMA drained; Ps[cur] free (reads done); Ps[cur^1] written

        // issue next K-tile DMA FIRST: full iteration of overlap before next loop-top drain
        if (it < 31) stageK(it + 1, cur ^ 1);

        __builtin_amdgcn_s_setprio(1);
        // PV for tile it-1: P from Ps[cur^1], V frags carried from last iteration.
        // Register-only MFMAs -> compiler overlaps them with the kf ds_reads below.
        if (it > 0) {
            #pragma unroll
            for (int mt = 0; mt < 8; ++mt) {
                bf16x8 pf = *(const bf16x8*)&Ps[cur ^ 1][mt * 16 + l16][quad * 8];
                #pragma unroll
                for (int nt = 0; nt < 4; ++nt)
                    oacc[mt][nt] = __builtin_amdgcn_mfma_f32_16x16x32_bf16(pf, vf[nt], oacc[mt][nt], 0, 0, 0);
            }
        }

        // V prefetch for THIS tile into the just-freed vf regs (16 VGPR, proven budget);
        // consumed at next iteration's PV -> QK^T + exp + barrier of latency cover
        #pragma unroll
        for (int nt = 0; nt < 4; ++nt)
            vf[nt] = *(const bf16x8*)(vptr + (size_t)nt * 16 * S_LEN + it * 32);

        // S = Q K^T  (B-frag: B[k=quad*8+j][n=lane&15] = K[key=lane&15][hd])
        f32x4 sacc[2];
        sacc[0] = zero; sacc[1] = zero;
        #pragma unroll
        for (int nt = 0; nt < 2; ++nt)
            #pragma unroll
            for (int t = 0; t < 16; ++t) {
                bf16x8 kf = *(const bf16x8*)&Ks[cur][(nt * 16 + l16) * KS_STRIDE + t * 32 + quad * 8];
                sacc[nt] = __builtin_amdgcn_mfma_f32_16x16x32_bf16(qf[t], kf, sacc[nt], 0, 0, 0);
            }
        __builtin_amdgcn_s_setprio(0);

        // p = exp(s) with fixed max 0; write to Ps[cur] (rows wave*16+quad*4+r)
        bool keep0 = mk0 != 0;
        bool keep1 = mk1 != 0;
        #pragma unroll
        for (int r = 0; r < 4; ++r) {
            float p0 = keep0 ? __expf(fminf(sacc[0][r] * scale, 30.f)) : 0.f;
            float p1 = keep1 ? __expf(fminf(sacc[1][r] * scale, 30.f)) : 0.f;
            lsum[r] += p0 + p1;
            Ps[cur][wave * 16 + quad * 4 + r][l16]      = (__bf16)p0;
            Ps[cur][wave * 16 + quad * 4 + r][16 + l16] = (__bf16)p1;
        }

        // prefetch mask for tile it+1 (full iteration of latency cover)
        if (head == 0 && it < 31) {
            int kn = split * 1024 + (it + 1) * 32;
            mk0 = mask[kn + l16];
            mk1 = mask[kn + 16 + l16];
        }
    }

    // epilogue PV for tile 31 (Ps[1], vf from it=31)
    __syncthreads();
    #pragma unroll
    for (int mt = 0; mt < 8; ++mt) {
        bf16x8 pf = *(const bf16x8*)&Ps[1][mt * 16 + l16][quad * 8];
        #pragma unroll
        for (int nt = 0; nt < 4; ++nt)
            oacc[mt][nt] = __builtin_amdgcn_mfma_f32_16x16x32_bf16(pf, vf[nt], oacc[mt][nt], 0, 0, 0);
    }

    // one l-reduction across the 16 lanes of this quad (rows wave*16 + quad*4 + r)
    #pragma unroll
    for (int r = 0; r < 4; ++r) {
        float s = lsum[r];
        #pragma unroll
        for (int off = 1; off < 16; off <<= 1)
            s += __shfl_xor(s, off, 64);
        lsum[r] = s;
    }
    int lrow = qtile * 128 + wave * 16 + quad * 4;
    if (l16 == 0) {
        #pragma unroll
        for (int r = 0; r < 4; ++r)
            Lbuf[(split * NHEAD + head) * S_LEN + lrow + r] = lsum[r];
    }
    // O epilogue: rows = qtile*128 + mt*16 + quad*4 + r, cols = head*512 + wave*64 + nt*16 + l16
    unsigned short* op = Opart + (size_t)split * S_LEN * HID;
    #pragma unroll
    for (int mt = 0; mt < 8; ++mt)
        #pragma unroll
        for (int nt = 0; nt < 4; ++nt)
            #pragma unroll
            for (int r = 0; r < 4; ++r)
                op[(qtile * 128 + mt * 16 + quad * 4 + r) * HID +
                   head * HDIM + wave * 64 + nt * 16 + l16] = f2b(oacc[mt][nt][r]);
}

// ---------------- per-row LayerNorm over H=1024 (fp32 in, fp32 out) ----------------
__global__ __launch_bounds__(256)
void k_ln(const float* __restrict__ res,
          const float* __restrict__ w,
          const float* __restrict__ b,
          float* __restrict__ out) {
    __shared__ float red[8];
    int s = blockIdx.x, tid = threadIdx.x;
    const float* row = res + s * HID;
    float x[4], s1 = 0.f, s2 = 0.f;
    #pragma unroll
    for (int i = 0; i < 4; ++i) {
        x[i] = row[tid + i * 256];
        s1 += x[i]; s2 += x[i] * x[i];
    }
    #pragma unroll
    for (int off = 1; off < 64; off <<= 1) {
        s1 += __shfl_xor(s1, off, 64);
        s2 += __shfl_xor(s2, off, 64);
    }
    int wave = tid >> 6;
    if ((tid & 63) == 0) { red[wave] = s1; red[4 + wave] = s2; }
    __syncthreads();
    s1 = red[0] + red[1] + red[2] + red[3];
    s2 = red[4] + red[5] + red[6] + red[7];
    float mu   = s1 * (1.f / HID);
    float var  = s2 * (1.f / HID) - mu * mu;
    float rstd = rsqrtf(var + LN_EPS);
    #pragma unroll
    for (int i = 0; i < 4; ++i) {
        int col = tid + i * 256;
        out[s * HID + col] = (x[i] - mu) * rstd * w[col] + b[col];
    }
}

extern "C" void kernel_launch(void* const* d_in, const int* in_sizes, int n_in,
                              void* d_out, int out_size, void* d_ws, size_t ws_size,
                              hipStream_t stream) {
    const float* X   = (const float*)d_in[0];
    const float* sd  = (const float*)d_in[1];
    const int*   msk = (const int*)d_in[2];
    const float* Wq  = (const float*)d_in[3];
    const float* Wk  = (const float*)d_in[4];
    const float* Wv  = (const float*)d_in[5];
    const float* Wo  = (const float*)d_in[6];
    const float* Wsp = (const float*)d_in[7];
    const float* bsp = (const float*)d_in[8];
    const float* lw  = (const float*)d_in[9];
    const float* lb  = (const float*)d_in[10];
    float* out = (float*)d_out;

    char* ws = (char*)d_ws;
    const size_t MB = 1ull << 20;
    float*          semb  = (float*)(ws);                     // 4 KB
    float*          Lbuf  = (float*)(ws + (1ull << 16));      // 128 KB @64K
    unsigned short* Xb    = (unsigned short*)(ws + 1 * MB);   // 8 MB bf16 X
    unsigned short* kvin  = (unsigned short*)(ws + 9 * MB);   // 8 MB
    unsigned short* Qb    = (unsigned short*)(ws + 17 * MB);  // 8 MB (dead after flash)
    unsigned short* Kb    = (unsigned short*)(ws + 25 * MB);  // 8 MB (dead after flash)
    unsigned short* Vt    = (unsigned short*)(ws + 33 * MB);  // 8 MB [HID][S_LEN]
    unsigned short* Wqb   = (unsigned short*)(ws + 49 * MB);  // 2 MB
    unsigned short* Wkb   = (unsigned short*)(ws + 51 * MB);  // 2 MB
    unsigned short* Wvb   = (unsigned short*)(ws + 53 * MB);  // 2 MB
    unsigned short* Wob   = (unsigned short*)(ws + 55 * MB);  // 2 MB
    float*          resf  = (float*)(ws + 17 * MB);           // 16 MB, overlays dead Qb/Kb
    unsigned short* Opart = (unsigned short*)(ws + 57 * MB);  // 32 MB bf16 [4][S][H] -> 89 MB total

    const int SH = S_LEN * HID;   // 4M
    const int WW = HID * HID;     // 1M

    // weights->bf16 (z=0..3) + semb (z=4) in one dispatch
    k_cvt4s<<<dim3(WW / 8 / 256, 5), dim3(256), 0, stream>>>(
        Wq, Wk, Wv, Wo, Wqb, Wkb, Wvb, Wob, Wsp, sd, bsp, semb);

    k_kvin<<<dim3(SH / 8 / 256), dim3(256), 0, stream>>>(X, semb, Xb, kvin);

    // fused Q/K/V projections, 128x128 tiles: z=0 Q, z=1 K, z=2 V^T  -> 768 blocks, 3/CU
    k_gemm_qkv<<<dim3(256, 1, 3), dim3(256), 0, stream>>>(Xb, kvin, Wqb, Wkb, Wvb, Qb, Kb, Vt);

    // XCD swizzle: x = head*NSPLIT+split (8), y = qtile (32); 256 blocks = 1/CU
    k_flash<<<dim3(NHEAD * NSPLIT, S_LEN / 128), dim3(512), 0, stream>>>(
        Qb, Kb, Vt, msk, Opart, Lbuf);

    // out-projection with fused split-combine + normalize + residual
    k_gemm_o<<<dim3(512), dim3(256), 0, stream>>>(Opart, Lbuf, Wob, resf, X);
    k_ln<<<dim3(S_LEN), dim3(256), 0, stream>>>(resf, lw, lb, out);
}

// Round 8
// 270.278 us; speedup vs baseline: 1.0005x; 1.0005x over previous
//
#include <hip/hip_runtime.h>
#include <stdint.h>

#define S_LEN  4096
#define HID    1024
#define NHEAD  2
#define HDIM   512
#define KS_STRIDE 520   // 512 + 8 pad elems -> bank-floor on QK^T reads
#define LN_EPS 1e-5f
#define PADK   4224     // compacted-key buffer width (>= 96*ceil(4096/96) = 4128)
#define CH1    832      // head-1 chunk: 5 splits x 832 covers 4096 (last split 768)

typedef __bf16 bf16x8 __attribute__((ext_vector_type(8)));
typedef float  f32x4  __attribute__((ext_vector_type(4)));

__device__ __forceinline__ float b2f(unsigned short u) {
    return __uint_as_float(((unsigned int)u) << 16);
}
__device__ __forceinline__ unsigned short f2b(float f) {
    unsigned int u = __float_as_uint(f);
    u += 0x7FFFu + ((u >> 16) & 1u);   // round-to-nearest-even
    return (unsigned short)(u >> 16);
}

// async 16B global->LDS (DMA; LDS dest must be wave-uniform base + lane*16)
__device__ __forceinline__ void async_cp16(const void* g, void* l) {
    __builtin_amdgcn_global_load_lds(
        (const __attribute__((address_space(1))) unsigned int*)g,
        (__attribute__((address_space(3))) unsigned int*)l, 16, 0, 0);
}

// ---- fp32->bf16 weights (z=0..3) + semb (z=4) + mask compaction scan (z=5) ----
__global__ void k_cvt4s(const float* __restrict__ i0, const float* __restrict__ i1,
                        const float* __restrict__ i2, const float* __restrict__ i3,
                        unsigned short* __restrict__ o0, unsigned short* __restrict__ o1,
                        unsigned short* __restrict__ o2, unsigned short* __restrict__ o3,
                        const float* __restrict__ Ws, const float* __restrict__ sd,
                        const float* __restrict__ bs, float* __restrict__ semb,
                        const int* __restrict__ msk, int* __restrict__ cidx,
                        int* __restrict__ nactp) {
    int z = blockIdx.y;
    if (z == 4) {
        int j = blockIdx.x * blockDim.x + threadIdx.x;
        if (j >= HID) return;
        float acc = bs[j];
        const float* row = Ws + j * 64;
        #pragma unroll
        for (int d = 0; d < 64; ++d) acc += row[d] * sd[d];
        semb[j] = acc;
        return;
    }
    if (z == 5) {   // compact head-0 active key indices (one block; serial scan, deterministic)
        if (blockIdx.x != 0) return;
        __shared__ int cnts[256];
        __shared__ int bases[256];
        int t = threadIdx.x;
        int c = 0;
        #pragma unroll
        for (int i = 0; i < 16; ++i) c += (msk[t * 16 + i] != 0);
        cnts[t] = c;
        __syncthreads();
        if (t == 0) {
            int b = 0;
            for (int k = 0; k < 256; ++k) { bases[k] = b; b += cnts[k]; }
            nactp[0] = b;
        }
        __syncthreads();
        int b = bases[t];
        #pragma unroll
        for (int i = 0; i < 16; ++i)
            if (msk[t * 16 + i] != 0) cidx[b++] = t * 16 + i;
        return;
    }
    const float* in = z == 0 ? i0 : z == 1 ? i1 : z == 2 ? i2 : i3;
    unsigned short* o = z == 0 ? o0 : z == 1 ? o1 : z == 2 ? o2 : o3;
    int i = (blockIdx.x * blockDim.x + threadIdx.x) * 8;
    float4 a = *(const float4*)(in + i);
    float4 b = *(const float4*)(in + i + 4);
    unsigned short r[8] = {f2b(a.x), f2b(a.y), f2b(a.z), f2b(a.w),
                           f2b(b.x), f2b(b.y), f2b(b.z), f2b(b.w)};
    *(uint4*)(o + i) = *(const uint4*)r;
}

// ---------------- Xb = bf16(X);  kv_in = bf16(X + semb) ----------------
__global__ void k_kvin(const float* __restrict__ X,
                       const float* __restrict__ semb,
                       unsigned short* __restrict__ Xb,
                       unsigned short* __restrict__ kv) {
    int idx = (blockIdx.x * blockDim.x + threadIdx.x) * 8;
    if (idx >= S_LEN * HID) return;
    int col = idx & (HID - 1);
    float4 a = *(const float4*)(X + idx);
    float4 b = *(const float4*)(X + idx + 4);
    unsigned short xo[8] = {f2b(a.x), f2b(a.y), f2b(a.z), f2b(a.w),
                            f2b(b.x), f2b(b.y), f2b(b.z), f2b(b.w)};
    *(uint4*)(Xb + idx) = *(const uint4*)xo;
    unsigned short o[8];
    o[0] = f2b(a.x + semb[col + 0]);
    o[1] = f2b(a.y + semb[col + 1]);
    o[2] = f2b(a.z + semb[col + 2]);
    o[3] = f2b(a.w + semb[col + 3]);
    o[4] = f2b(b.x + semb[col + 4]);
    o[5] = f2b(b.y + semb[col + 5]);
    o[6] = f2b(b.z + semb[col + 6]);
    o[7] = f2b(b.w + semb[col + 7]);
    *(uint4*)(kv + idx) = *(const uint4*)o;
}

// ---------------- 128x128 GEMM core: C = A @ B^T, bf16 out (R15 dbuf pipeline) ----------------
__device__ __forceinline__
void gemm128(const unsigned short* __restrict__ A,
             const unsigned short* __restrict__ B,
             unsigned short* __restrict__ Cb,
             int bx, int nx, int ldc) {
    __shared__ unsigned short As[2][128 * 32];
    __shared__ unsigned short Bs[2][128 * 32];
    int tid  = threadIdx.x;
    int wave = tid >> 6, lane = tid & 63;
    int quad = lane >> 4, l16 = lane & 15;
    int wm = wave >> 1, wn = wave & 1;
    int m0 = (bx / nx) * 128, n0 = (bx % nx) * 128;

    auto stage = [&](int k0, int b) {
        #pragma unroll
        for (int i = 0; i < 2; ++i) {
            int c = tid + i * 256;   // LDS dest c*16B: wave-uniform base + lane*16 -> DMA-legal
            async_cp16(A + (m0 + (c >> 2)) * HID + k0 + (c & 3) * 8, As[b] + c * 8);
            async_cp16(B + (n0 + (c >> 2)) * HID + k0 + (c & 3) * 8, Bs[b] + c * 8);
        }
    };

    f32x4 zero = {0.f, 0.f, 0.f, 0.f};
    f32x4 acc[4][4];
    #pragma unroll
    for (int i = 0; i < 4; ++i)
        #pragma unroll
        for (int j = 0; j < 4; ++j) acc[i][j] = zero;

    stage(0, 0);
    for (int it = 0; it < HID / 32; ++it) {
        int b = it & 1;
        __syncthreads();
        if (it + 1 < HID / 32) stage((it + 1) * 32, b ^ 1);

        bf16x8 af[4], bfr[4];
        #pragma unroll
        for (int i = 0; i < 4; ++i)
            af[i] = *(const bf16x8*)(As[b] + (wm * 64 + i * 16 + l16) * 32 + quad * 8);
        #pragma unroll
        for (int j = 0; j < 4; ++j)
            bfr[j] = *(const bf16x8*)(Bs[b] + (wn * 64 + j * 16 + l16) * 32 + quad * 8);
        #pragma unroll
        for (int i = 0; i < 4; ++i)
            #pragma unroll
            for (int j = 0; j < 4; ++j)
                acc[i][j] = __builtin_amdgcn_mfma_f32_16x16x32_bf16(af[i], bfr[j], acc[i][j], 0, 0, 0);
    }

    #pragma unroll
    for (int i = 0; i < 4; ++i) {
        int rbase = m0 + wm * 64 + i * 16 + quad * 4;
        #pragma unroll
        for (int j = 0; j < 4; ++j) {
            int col = n0 + wn * 64 + j * 16 + l16;
            #pragma unroll
            for (int r = 0; r < 4; ++r)
                Cb[(size_t)(rbase + r) * ldc + col] = f2b(acc[i][j][r]);
        }
    }
}

__global__ __launch_bounds__(256)
void k_gemm_qkv(const unsigned short* __restrict__ Xb,
                const unsigned short* __restrict__ kvin,
                const unsigned short* __restrict__ Wqb,
                const unsigned short* __restrict__ Wkb,
                const unsigned short* __restrict__ Wvb,
                unsigned short* __restrict__ Qb,
                unsigned short* __restrict__ Kb,
                unsigned short* __restrict__ Vt) {
    int bx = (blockIdx.x & 7) * 32 + (blockIdx.x >> 3);
    int z = blockIdx.z;
    if (z == 0)      gemm128(Xb,   Wqb,  Qb,  bx,  8, HID);
    else if (z == 1) gemm128(kvin, Wkb,  Kb,  bx,  8, HID);
    else             gemm128(Wvb,  kvin, Vt,  bx, 32, S_LEN);   // V^T [HID][S_LEN]
}

// ---- gather compacted head-0 K rows and V^T cols (zero-padded beyond nact) ----
// Writes overlay the DEAD Xb/kvin region (both only read by k_gemm_qkv, which precedes).
__global__ __launch_bounds__(256)
void k_gather(const unsigned short* __restrict__ Kb,
              const unsigned short* __restrict__ Vt,
              const int* __restrict__ cidx,
              const int* __restrict__ nactp,
              unsigned short* __restrict__ Kc,     // [PADK][512]
              unsigned short* __restrict__ Vtc) {  // [512][PADK]
    int nact = nactp[0];
    int gid = blockIdx.x * 256 + threadIdx.x;
    int idx = gid * 8;
    if (blockIdx.y == 0) {
        int j = idx >> 9, d = idx & 511;         // head-0 = K cols 0..511
        uint4 v = {0u, 0u, 0u, 0u};
        if (j < nact) v = *(const uint4*)(Kb + (size_t)cidx[j] * HID + d);
        *(uint4*)(Kc + (size_t)j * 512 + d) = v;
    } else {
        int d = idx / PADK, j0 = idx % PADK;     // head-0 = Vt rows 0..511
        unsigned short o[8];
        #pragma unroll
        for (int i = 0; i < 8; ++i) {
            int j = j0 + i;
            o[i] = (j < nact) ? Vt[(size_t)d * S_LEN + cidx[j]] : (unsigned short)0;
        }
        *(uint4*)(Vtc + (size_t)d * PADK + j0) = *(const uint4*)o;
    }
}

// ------- out-projection 64x128 tile, fused split-combine + normalize + residual -------
// Opart layout: head0 slots 0..2, head1 slots 3..7, each [S][512] (per-head local cols).
__global__ __launch_bounds__(256)
void k_gemm_o(const unsigned short* __restrict__ Opart,
              const float* __restrict__ Lbuf,    // [8][S]
              const unsigned short* __restrict__ B,
              float* __restrict__ Cf,
              const float* __restrict__ Xres) {
    __shared__ unsigned short As[2][64 * 32];
    __shared__ unsigned short Bs[2][128 * 32];
    const size_t SH2 = (size_t)S_LEN * 512;
    int tid  = threadIdx.x;
    int wave = tid >> 6, lane = tid & 63;
    int quad = lane >> 4, l16 = lane & 15;
    int bx = (blockIdx.x & 7) * 64 + (blockIdx.x >> 3);
    int m0 = (bx >> 3) * 64, n0 = (bx & 7) * 128;

    int arow  = m0 + (tid >> 2);
    int acol8 = (tid & 3) * 8;
    float rinv[NHEAD];
    {
        float l0 = Lbuf[arow] + Lbuf[S_LEN + arow] + Lbuf[2 * S_LEN + arow];
        float l1 = 0.f;
        #pragma unroll
        for (int z = 3; z < 8; ++z) l1 += Lbuf[z * S_LEN + arow];
        rinv[0] = 1.f / l0;
        rinv[1] = 1.f / l1;
    }

    auto stageB = [&](int k0, int b) {
        #pragma unroll
        for (int i = 0; i < 2; ++i) {
            int c = tid + i * 256;
            async_cp16(B + (n0 + (c >> 2)) * HID + k0 + (c & 3) * 8, Bs[b] + c * 8);
        }
    };
    auto stageA = [&](int k0, int b) {
        int h = k0 >> 9;
        float rv = rinv[h];
        int lk = (k0 & 511) + acol8;
        const unsigned short* ap = Opart + (h ? 3 * SH2 : 0) + (size_t)arow * 512 + lk;
        float s[8] = {0.f, 0.f, 0.f, 0.f, 0.f, 0.f, 0.f, 0.f};
        int nz = h ? 5 : 3;
        for (int z = 0; z < nz; ++z) {
            uint4 v = *(const uint4*)(ap + (size_t)z * SH2);
            unsigned short us[8];
            *(uint4*)us = v;
            #pragma unroll
            for (int e = 0; e < 8; ++e) s[e] += b2f(us[e]);
        }
        unsigned short o8[8];
        #pragma unroll
        for (int e = 0; e < 8; ++e) o8[e] = f2b(s[e] * rv);
        *(uint4*)(As[b] + tid * 8) = *(const uint4*)o8;
    };

    f32x4 zero = {0.f, 0.f, 0.f, 0.f};
    f32x4 acc[4][2];
    #pragma unroll
    for (int i = 0; i < 4; ++i)
        #pragma unroll
        for (int j = 0; j < 2; ++j) acc[i][j] = zero;

    stageB(0, 0);
    stageA(0, 0);
    for (int it = 0; it < HID / 32; ++it) {
        int b = it & 1;
        __syncthreads();
        if (it + 1 < HID / 32) {
            stageB((it + 1) * 32, b ^ 1);
            stageA((it + 1) * 32, b ^ 1);
        }
        bf16x8 af[4], bfr[2];
        #pragma unroll
        for (int i = 0; i < 4; ++i)
            af[i] = *(const bf16x8*)(As[b] + (i * 16 + l16) * 32 + quad * 8);
        #pragma unroll
        for (int j = 0; j < 2; ++j)
            bfr[j] = *(const bf16x8*)(Bs[b] + (wave * 32 + j * 16 + l16) * 32 + quad * 8);
        #pragma unroll
        for (int i = 0; i < 4; ++i)
            #pragma unroll
            for (int j = 0; j < 2; ++j)
                acc[i][j] = __builtin_amdgcn_mfma_f32_16x16x32_bf16(af[i], bfr[j], acc[i][j], 0, 0, 0);
    }

    #pragma unroll
    for (int i = 0; i < 4; ++i) {
        int rbase = m0 + i * 16 + quad * 4;
        #pragma unroll
        for (int j = 0; j < 2; ++j) {
            int col = n0 + wave * 32 + j * 16 + l16;
            #pragma unroll
            for (int r = 0; r < 4; ++r) {
                size_t o = (size_t)(rbase + r) * HID + col;
                Cf[o] = acc[i][j][r] + Xres[o];
            }
        }
    }
}

// ---------------- flash attention: 128 queries x one (head, key-split) ----------------
// R17 = R16 logic, workspace repacked to the PROVEN 89MB envelope (R16's 91MB layout is
// the prime suspect for the replay-only divergence: OOB Opart writes would be harmless on
// the pre-graph check launch but corrupt post-launch allocations during graph replays).
// head-0: compacted keys (Kc/Vtc), 3 splits; head-1: all 4096 keys, 5 splits (CH1=832).
// Inner loop = R12-proven pipeline; validity = (key < nact); zero-padded tails.
__global__ __launch_bounds__(512, 2)
void k_flash(const unsigned short* __restrict__ Q,
             const unsigned short* __restrict__ Kb,
             const unsigned short* __restrict__ Vt,    // [HID][S_LEN]
             const unsigned short* __restrict__ Kc,    // [PADK][512] compacted head-0 K
             const unsigned short* __restrict__ Vtc,   // [512][PADK] compacted head-0 V^T
             const int* __restrict__ nactp,
             unsigned short* __restrict__ Opart,       // [8][S][512] per-head local cols
             float* __restrict__ Lbuf) {               // [8][S]
    __shared__ unsigned short Ks[2][32 * KS_STRIDE];
    __shared__ __bf16 Ps[2][128][40];
    int tid  = threadIdx.x;
    int wave = tid >> 6, lane = tid & 63;
    int quad = lane >> 4, l16 = lane & 15;
    int x = blockIdx.x, qtile = blockIdx.y;
    int head  = (x >= 3) ? 1 : 0;
    int split = head ? x - 3 : x;
    int nact  = nactp[0];

    int nit, base, krs, vrs;
    const unsigned short *Ksrc, *Vsrc;
    if (head == 0) {
        nit  = (nact + 95) / 96;          // ceil(nact / (3 splits * 32))
        base = split * nit * 32;
        Ksrc = Kc;  krs = 512;
        Vsrc = Vtc; vrs = PADK;
    } else {
        base = split * CH1;
        nit  = min(CH1 >> 5, (S_LEN - base) >> 5);
        Ksrc = Kb + HDIM;  krs = HID;     // head-1 K cols 512..1023
        Vsrc = Vt + (size_t)HDIM * S_LEN; // head-1 Vt rows 512..1023
        vrs  = S_LEN;
    }

    // Q fragments (A-operand: A[m=lane&15][k=quad*8+j]), pinned in registers
    int qrow = qtile * 128 + wave * 16 + l16;
    const unsigned short* qp = Q + qrow * HID + head * HDIM;
    bf16x8 qf[16];
    #pragma unroll
    for (int t = 0; t < 16; ++t) qf[t] = *(const bf16x8*)(qp + t * 32 + quad * 8);

    float lsum[4];
    #pragma unroll
    for (int r = 0; r < 4; ++r) lsum[r] = 0.f;
    f32x4 zero = {0.f, 0.f, 0.f, 0.f};
    f32x4 oacc[8][4];
    #pragma unroll
    for (int mt = 0; mt < 8; ++mt)
        #pragma unroll
        for (int nt = 0; nt < 4; ++nt) oacc[mt][nt] = zero;

    const float scale = 0.044194173824159216f; // 1/sqrt(512)
    const unsigned short* vptr = Vsrc + (size_t)(wave * 64 + l16) * vrs + base + quad * 8;

    auto stageK = [&](int kt, int buf) {
        int kb = base + kt * 32;
        #pragma unroll
        for (int i = 0; i < 4; ++i) {
            int c = tid + i * 512;
            int row = c >> 6, col = (c & 63) * 8;   // per-wave: row uniform, col = lane*16B
            async_cp16(Ksrc + (size_t)(kb + row) * krs + col, &Ks[buf][row * KS_STRIDE + col]);
        }
    };

    if (nit > 0) stageK(0, 0);

    bf16x8 vf[4];
    for (int it = 0; it < nit; ++it) {
        int cur = it & 1;
        __syncthreads();   // Ks[cur] DMA drained; Ps[cur] free; Ps[cur^1] written

        if (it + 1 < nit) stageK(it + 1, cur ^ 1);

        __builtin_amdgcn_s_setprio(1);
        if (it > 0) {
            #pragma unroll
            for (int mt = 0; mt < 8; ++mt) {
                bf16x8 pf = *(const bf16x8*)&Ps[cur ^ 1][mt * 16 + l16][quad * 8];
                #pragma unroll
                for (int nt = 0; nt < 4; ++nt)
                    oacc[mt][nt] = __builtin_amdgcn_mfma_f32_16x16x32_bf16(pf, vf[nt], oacc[mt][nt], 0, 0, 0);
            }
        }

        // V prefetch for THIS tile (16 VGPR carry, proven budget)
        #pragma unroll
        for (int nt = 0; nt < 4; ++nt)
            vf[nt] = *(const bf16x8*)(vptr + (size_t)nt * 16 * vrs + it * 32);

        // S = Q K^T
        f32x4 sacc[2];
        sacc[0] = zero; sacc[1] = zero;
        #pragma unroll
        for (int nt = 0; nt < 2; ++nt)
            #pragma unroll
            for (int t = 0; t < 16; ++t) {
                bf16x8 kf = *(const bf16x8*)&Ks[cur][(nt * 16 + l16) * KS_STRIDE + t * 32 + quad * 8];
                sacc[nt] = __builtin_amdgcn_mfma_f32_16x16x32_bf16(qf[t], kf, sacc[nt], 0, 0, 0);
            }
        __builtin_amdgcn_s_setprio(0);

        // validity: compacted head-0 keys need only the nact bound; head-1 all valid
        bool keep0 = true, keep1 = true;
        if (head == 0) {
            int kb = base + it * 32;
            keep0 = kb + l16 < nact;
            keep1 = kb + 16 + l16 < nact;
        }
        #pragma unroll
        for (int r = 0; r < 4; ++r) {
            float p0 = keep0 ? __expf(fminf(sacc[0][r] * scale, 30.f)) : 0.f;
            float p1 = keep1 ? __expf(fminf(sacc[1][r] * scale, 30.f)) : 0.f;
            lsum[r] += p0 + p1;
            Ps[cur][wave * 16 + quad * 4 + r][l16]      = (__bf16)p0;
            Ps[cur][wave * 16 + quad * 4 + r][16 + l16] = (__bf16)p1;
        }
    }

    // epilogue PV for the last tile
    if (nit > 0) {
        int lastb = (nit - 1) & 1;
        __syncthreads();
        #pragma unroll
        for (int mt = 0; mt < 8; ++mt) {
            bf16x8 pf = *(const bf16x8*)&Ps[lastb][mt * 16 + l16][quad * 8];
            #pragma unroll
            for (int nt = 0; nt < 4; ++nt)
                oacc[mt][nt] = __builtin_amdgcn_mfma_f32_16x16x32_bf16(pf, vf[nt], oacc[mt][nt], 0, 0, 0);
        }
    }

    // l-reduction across the 16 lanes of this quad
    #pragma unroll
    for (int r = 0; r < 4; ++r) {
        float s = lsum[r];
        #pragma unroll
        for (int off = 1; off < 16; off <<= 1)
            s += __shfl_xor(s, off, 64);
        lsum[r] = s;
    }
    int slot = head ? 3 + split : split;
    int lrow = qtile * 128 + wave * 16 + quad * 4;
    if (l16 == 0) {
        #pragma unroll
        for (int r = 0; r < 4; ++r)
            Lbuf[slot * S_LEN + lrow + r] = lsum[r];
    }
    // O epilogue: per-head local cols (512-wide)
    unsigned short* op = Opart + (size_t)slot * S_LEN * 512;
    #pragma unroll
    for (int mt = 0; mt < 8; ++mt)
        #pragma unroll
        for (int nt = 0; nt < 4; ++nt)
            #pragma unroll
            for (int r = 0; r < 4; ++r)
                op[(qtile * 128 + mt * 16 + quad * 4 + r) * 512 +
                   wave * 64 + nt * 16 + l16] = f2b(oacc[mt][nt][r]);
}

// ---------------- per-row LayerNorm over H=1024 (fp32 in, fp32 out) ----------------
__global__ __launch_bounds__(256)
void k_ln(const float* __restrict__ res,
          const float* __restrict__ w,
          const float* __restrict__ b,
          float* __restrict__ out) {
    __shared__ float red[8];
    int s = blockIdx.x, tid = threadIdx.x;
    const float* row = res + s * HID;
    float x[4], s1 = 0.f, s2 = 0.f;
    #pragma unroll
    for (int i = 0; i < 4; ++i) {
        x[i] = row[tid + i * 256];
        s1 += x[i]; s2 += x[i] * x[i];
    }
    #pragma unroll
    for (int off = 1; off < 64; off <<= 1) {
        s1 += __shfl_xor(s1, off, 64);
        s2 += __shfl_xor(s2, off, 64);
    }
    int wave = tid >> 6;
    if ((tid & 63) == 0) { red[wave] = s1; red[4 + wave] = s2; }
    __syncthreads();
    s1 = red[0] + red[1] + red[2] + red[3];
    s2 = red[4] + red[5] + red[6] + red[7];
    float mu   = s1 * (1.f / HID);
    float var  = s2 * (1.f / HID) - mu * mu;
    float rstd = rsqrtf(var + LN_EPS);
    #pragma unroll
    for (int i = 0; i < 4; ++i) {
        int col = tid + i * 256;
        out[s * HID + col] = (x[i] - mu) * rstd * w[col] + b[col];
    }
}

extern "C" void kernel_launch(void* const* d_in, const int* in_sizes, int n_in,
                              void* d_out, int out_size, void* d_ws, size_t ws_size,
                              hipStream_t stream) {
    const float* X   = (const float*)d_in[0];
    const float* sd  = (const float*)d_in[1];
    const int*   msk = (const int*)d_in[2];
    const float* Wq  = (const float*)d_in[3];
    const float* Wk  = (const float*)d_in[4];
    const float* Wv  = (const float*)d_in[5];
    const float* Wo  = (const float*)d_in[6];
    const float* Wsp = (const float*)d_in[7];
    const float* bsp = (const float*)d_in[8];
    const float* lw  = (const float*)d_in[9];
    const float* lb  = (const float*)d_in[10];
    float* out = (float*)d_out;

    // Workspace map — 89MB total, identical envelope to the R0..R6-proven layouts.
    // Kc/Vtc TIME-SHARE the Xb/kvin region: kvin writes -> qkv reads -> gather overwrites
    // with Kc/Vtc -> flash reads. No cross-launch hazard (kvin rewrites each launch).
    char* ws = (char*)d_ws;
    const size_t MB = 1ull << 20;
    float*          semb  = (float*)(ws);                     // 4 KB @0
    int*            cidx  = (int*)(ws + (16 << 10));          // 16 KB @16K
    int*            nactp = (int*)(ws + (48 << 10));          // 4 B  @48K
    float*          Lbuf  = (float*)(ws + (1ull << 16));      // 128 KB @64K (8 slots x S)
    unsigned short* Xb    = (unsigned short*)(ws + 1 * MB);   // 8 MB bf16 X (dead after qkv)
    unsigned short* kvin  = (unsigned short*)(ws + 9 * MB);   // 8 MB (dead after qkv)
    unsigned short* Kc    = (unsigned short*)(ws + 1 * MB);   // 4.125 MB, overlays dead Xb
    unsigned short* Vtc   = (unsigned short*)(ws + 5 * MB + (256 << 10)); // 4.125 MB @5.25M
    unsigned short* Qb    = (unsigned short*)(ws + 17 * MB);  // 8 MB (dead after flash)
    unsigned short* Kb    = (unsigned short*)(ws + 25 * MB);  // 8 MB (dead after flash)
    unsigned short* Vt    = (unsigned short*)(ws + 33 * MB);  // 8 MB [HID][S_LEN]
    unsigned short* Wqb   = (unsigned short*)(ws + 49 * MB);  // 2 MB
    unsigned short* Wkb   = (unsigned short*)(ws + 51 * MB);  // 2 MB
    unsigned short* Wvb   = (unsigned short*)(ws + 53 * MB);  // 2 MB
    unsigned short* Wob   = (unsigned short*)(ws + 55 * MB);  // 2 MB
    float*          resf  = (float*)(ws + 17 * MB);           // 16 MB, overlays dead Qb/Kb
    unsigned short* Opart = (unsigned short*)(ws + 57 * MB);  // 32 MB [8][S][512] -> 89 MB total

    const int SH = S_LEN * HID;   // 4M
    const int WW = HID * HID;     // 1M

    // weights->bf16 (z=0..3) + semb (z=4) + mask compaction (z=5)
    k_cvt4s<<<dim3(WW / 8 / 256, 6), dim3(256), 0, stream>>>(
        Wq, Wk, Wv, Wo, Wqb, Wkb, Wvb, Wob, Wsp, sd, bsp, semb, msk, cidx, nactp);

    k_kvin<<<dim3(SH / 8 / 256), dim3(256), 0, stream>>>(X, semb, Xb, kvin);

    // fused Q/K/V projections, 128x128 tiles -> 768 blocks, 3/CU
    k_gemm_qkv<<<dim3(256, 1, 3), dim3(256), 0, stream>>>(Xb, kvin, Wqb, Wkb, Wvb, Qb, Kb, Vt);

    // compact head-0 K rows / V^T cols (PADK*512 elems per plane, 8/thread)
    k_gather<<<dim3(PADK * 512 / 8 / 256, 2), dim3(256), 0, stream>>>(
        Kb, Vt, cidx, nactp, Kc, Vtc);

    // asymmetric splits: x 0..2 = head0 (compacted), x 3..7 = head1; y = qtile (32)
    k_flash<<<dim3(8, S_LEN / 128), dim3(512), 0, stream>>>(
        Qb, Kb, Vt, Kc, Vtc, nactp, Opart, Lbuf);

    // out-projection with fused split-combine + normalize + residual
    k_gemm_o<<<dim3(512), dim3(256), 0, stream>>>(Opart, Lbuf, Wob, resf, X);
    k_ln<<<dim3(S_LEN), dim3(256), 0, stream>>>(resf, lw, lb, out);
}

// Round 9
// 269.013 us; speedup vs baseline: 1.0052x; 1.0047x over previous
//
#include <hip/hip_runtime.h>
#include <stdint.h>

#define S_LEN  4096
#define HID    1024
#define NHEAD  2
#define HDIM   512
#define KS_STRIDE 520   // 512 + 8 pad elems -> bank-floor on QK^T reads
#define LN_EPS 1e-5f
#define PADK   4224     // compacted-key buffer rows (33*128; >= 3*ceil(4096/96)*32 = 4128)
#define CH1    832      // head-1 chunk: 5 splits x 832 covers 4096 (last split 768)

typedef __bf16 bf16x8 __attribute__((ext_vector_type(8)));
typedef float  f32x4  __attribute__((ext_vector_type(4)));

__device__ __forceinline__ float b2f(unsigned short u) {
    return __uint_as_float(((unsigned int)u) << 16);
}
__device__ __forceinline__ unsigned short f2b(float f) {
    unsigned int u = __float_as_uint(f);
    u += 0x7FFFu + ((u >> 16) & 1u);   // round-to-nearest-even
    return (unsigned short)(u >> 16);
}

// async 16B global->LDS (DMA; LDS dest must be wave-uniform base + lane*16;
// the GLOBAL source is per-lane -> index remap through cidx is legal)
__device__ __forceinline__ void async_cp16(const void* g, void* l) {
    __builtin_amdgcn_global_load_lds(
        (const __attribute__((address_space(1))) unsigned int*)g,
        (__attribute__((address_space(3))) unsigned int*)l, 16, 0, 0);
}

// ---- fp32->bf16 weights (z=0..3) + semb (z=4) + mask compaction scan (z=5) ----
__global__ void k_cvt4s(const float* __restrict__ i0, const float* __restrict__ i1,
                        const float* __restrict__ i2, const float* __restrict__ i3,
                        unsigned short* __restrict__ o0, unsigned short* __restrict__ o1,
                        unsigned short* __restrict__ o2, unsigned short* __restrict__ o3,
                        const float* __restrict__ Ws, const float* __restrict__ sd,
                        const float* __restrict__ bs, float* __restrict__ semb,
                        const int* __restrict__ msk, int* __restrict__ cidx,
                        int* __restrict__ nactp) {
    int z = blockIdx.y;
    if (z == 4) {
        int j = blockIdx.x * blockDim.x + threadIdx.x;
        if (j >= HID) return;
        float acc = bs[j];
        const float* row = Ws + j * 64;
        #pragma unroll
        for (int d = 0; d < 64; ++d) acc += row[d] * sd[d];
        semb[j] = acc;
        return;
    }
    if (z == 5) {   // compact head-0 active key indices; zero-fill tail to PADK
        if (blockIdx.x != 0) return;
        __shared__ int cnts[256];
        __shared__ int bases[256];
        __shared__ int nact_s;
        int t = threadIdx.x;
        int c = 0;
        #pragma unroll
        for (int i = 0; i < 16; ++i) c += (msk[t * 16 + i] != 0);
        cnts[t] = c;
        __syncthreads();
        if (t == 0) {
            int b = 0;
            for (int k = 0; k < 256; ++k) { bases[k] = b; b += cnts[k]; }
            nactp[0] = b;
            nact_s   = b;
        }
        __syncthreads();
        int b = bases[t];
        #pragma unroll
        for (int i = 0; i < 16; ++i)
            if (msk[t * 16 + i] != 0) cidx[b++] = t * 16 + i;
        // tail -> key 0 (valid finite data; P-gate zeroes its contribution)
        for (int j = nact_s + t; j < PADK; j += 256) cidx[j] = 0;
        return;
    }
    const float* in = z == 0 ? i0 : z == 1 ? i1 : z == 2 ? i2 : i3;
    unsigned short* o = z == 0 ? o0 : z == 1 ? o1 : z == 2 ? o2 : o3;
    int i = (blockIdx.x * blockDim.x + threadIdx.x) * 8;
    float4 a = *(const float4*)(in + i);
    float4 b = *(const float4*)(in + i + 4);
    unsigned short r[8] = {f2b(a.x), f2b(a.y), f2b(a.z), f2b(a.w),
                           f2b(b.x), f2b(b.y), f2b(b.z), f2b(b.w)};
    *(uint4*)(o + i) = *(const uint4*)r;
}

// ---------------- Xb = bf16(X);  kv_in = bf16(X + semb) ----------------
__global__ void k_kvin(const float* __restrict__ X,
                       const float* __restrict__ semb,
                       unsigned short* __restrict__ Xb,
                       unsigned short* __restrict__ kv) {
    int idx = (blockIdx.x * blockDim.x + threadIdx.x) * 8;
    if (idx >= S_LEN * HID) return;
    int col = idx & (HID - 1);
    float4 a = *(const float4*)(X + idx);
    float4 b = *(const float4*)(X + idx + 4);
    unsigned short xo[8] = {f2b(a.x), f2b(a.y), f2b(a.z), f2b(a.w),
                            f2b(b.x), f2b(b.y), f2b(b.z), f2b(b.w)};
    *(uint4*)(Xb + idx) = *(const uint4*)xo;
    unsigned short o[8];
    o[0] = f2b(a.x + semb[col + 0]);
    o[1] = f2b(a.y + semb[col + 1]);
    o[2] = f2b(a.z + semb[col + 2]);
    o[3] = f2b(a.w + semb[col + 3]);
    o[4] = f2b(b.x + semb[col + 4]);
    o[5] = f2b(b.y + semb[col + 5]);
    o[6] = f2b(b.z + semb[col + 6]);
    o[7] = f2b(b.w + semb[col + 7]);
    *(uint4*)(kv + idx) = *(const uint4*)o;
}

// ---------------- 128x128 GEMM core: C = A @ B^T, bf16 out (R15 dbuf pipeline) ----------------
// ra/rb optionally remap the STAGED A/B row index through an index table (gathered GEMM).
// Output rows/cols are never remapped. Both operands always have row stride HID.
__device__ __forceinline__
void gemm128(const unsigned short* __restrict__ A,
             const unsigned short* __restrict__ B,
             unsigned short* __restrict__ Cb,
             int bx, int nx, int ldc,
             const int* __restrict__ ra, const int* __restrict__ rb) {
    __shared__ unsigned short As[2][128 * 32];
    __shared__ unsigned short Bs[2][128 * 32];
    int tid  = threadIdx.x;
    int wave = tid >> 6, lane = tid & 63;
    int quad = lane >> 4, l16 = lane & 15;
    int wm = wave >> 1, wn = wave & 1;
    int m0 = (bx / nx) * 128, n0 = (bx % nx) * 128;

    auto stage = [&](int k0, int b) {
        #pragma unroll
        for (int i = 0; i < 2; ++i) {
            int c = tid + i * 256;   // LDS dest c*16B: wave-uniform base + lane*16 -> DMA-legal
            int arow = m0 + (c >> 2);
            if (ra) arow = ra[arow];
            int brow = n0 + (c >> 2);
            if (rb) brow = rb[brow];
            async_cp16(A + (size_t)arow * HID + k0 + (c & 3) * 8, As[b] + c * 8);
            async_cp16(B + (size_t)brow * HID + k0 + (c & 3) * 8, Bs[b] + c * 8);
        }
    };

    f32x4 zero = {0.f, 0.f, 0.f, 0.f};
    f32x4 acc[4][4];
    #pragma unroll
    for (int i = 0; i < 4; ++i)
        #pragma unroll
        for (int j = 0; j < 4; ++j) acc[i][j] = zero;

    stage(0, 0);
    for (int it = 0; it < HID / 32; ++it) {
        int b = it & 1;
        __syncthreads();
        if (it + 1 < HID / 32) stage((it + 1) * 32, b ^ 1);

        bf16x8 af[4], bfr[4];
        #pragma unroll
        for (int i = 0; i < 4; ++i)
            af[i] = *(const bf16x8*)(As[b] + (wm * 64 + i * 16 + l16) * 32 + quad * 8);
        #pragma unroll
        for (int j = 0; j < 4; ++j)
            bfr[j] = *(const bf16x8*)(Bs[b] + (wn * 64 + j * 16 + l16) * 32 + quad * 8);
        #pragma unroll
        for (int i = 0; i < 4; ++i)
            #pragma unroll
            for (int j = 0; j < 4; ++j)
                acc[i][j] = __builtin_amdgcn_mfma_f32_16x16x32_bf16(af[i], bfr[j], acc[i][j], 0, 0, 0);
    }

    #pragma unroll
    for (int i = 0; i < 4; ++i) {
        int rbase = m0 + wm * 64 + i * 16 + quad * 4;
        #pragma unroll
        for (int j = 0; j < 4; ++j) {
            int col = n0 + wn * 64 + j * 16 + l16;
            #pragma unroll
            for (int r = 0; r < 4; ++r)
                Cb[(size_t)(rbase + r) * ldc + col] = f2b(acc[i][j][r]);
        }
    }
}

// All projections in one flat launch (R18): Q full; K/V only the head-1 halves; the
// head-0 halves are produced DIRECTLY COMPACTED via cidx-remapped staging (kills the
// R8 gather kernel and its 2.16M scattered 2B reads). 776 = 8*97 blocks, XCD-swizzled.
__global__ __launch_bounds__(256)
void k_gemms(const unsigned short* __restrict__ Xb,
             const unsigned short* __restrict__ kvin,
             const unsigned short* __restrict__ Wqb,
             const unsigned short* __restrict__ Wkb,
             const unsigned short* __restrict__ Wvb,
             const int* __restrict__ cidx,
             unsigned short* __restrict__ Qb,
             unsigned short* __restrict__ Kb1,   // [S_LEN][512]  head-1 K
             unsigned short* __restrict__ Vt1,   // [512][S_LEN]  head-1 V^T
             unsigned short* __restrict__ Kc,    // [PADK][512]   compacted head-0 K
             unsigned short* __restrict__ Vtc) { // [512][PADK]   compacted head-0 V^T
    int g = blockIdx.x;
    int b = (g & 7) * 97 + (g >> 3);   // bijective XCD swizzle (776 % 8 == 0)
    if (b < 256)      gemm128(Xb,   Wqb,             Qb,  b,        8, HID,   nullptr, nullptr);
    else if (b < 384) gemm128(kvin, Wkb + 512 * HID, Kb1, b - 256,  4, 512,   nullptr, nullptr);
    else if (b < 512) gemm128(Wvb + 512 * HID, kvin, Vt1, b - 384, 32, S_LEN, nullptr, nullptr);
    else if (b < 644) gemm128(kvin, Wkb,             Kc,  b - 512,  4, 512,   cidx,    nullptr);
    else              gemm128(Wvb,  kvin,            Vtc, b - 644, 33, PADK,  nullptr, cidx);
}

// ------- out-projection 64x128 tile, fused split-combine + normalize + residual -------
// Opart layout: head0 slots 0..2, head1 slots 3..7, each [S][512] (per-head local cols).
__global__ __launch_bounds__(256)
void k_gemm_o(const unsigned short* __restrict__ Opart,
              const float* __restrict__ Lbuf,    // [8][S]
              const unsigned short* __restrict__ B,
              float* __restrict__ Cf,
              const float* __restrict__ Xres) {
    __shared__ unsigned short As[2][64 * 32];
    __shared__ unsigned short Bs[2][128 * 32];
    const size_t SH2 = (size_t)S_LEN * 512;
    int tid  = threadIdx.x;
    int wave = tid >> 6, lane = tid & 63;
    int quad = lane >> 4, l16 = lane & 15;
    int bx = (blockIdx.x & 7) * 64 + (blockIdx.x >> 3);
    int m0 = (bx >> 3) * 64, n0 = (bx & 7) * 128;

    int arow  = m0 + (tid >> 2);
    int acol8 = (tid & 3) * 8;
    float rinv[NHEAD];
    {
        float l0 = Lbuf[arow] + Lbuf[S_LEN + arow] + Lbuf[2 * S_LEN + arow];
        float l1 = 0.f;
        #pragma unroll
        for (int z = 3; z < 8; ++z) l1 += Lbuf[z * S_LEN + arow];
        rinv[0] = 1.f / l0;
        rinv[1] = 1.f / l1;
    }

    auto stageB = [&](int k0, int b) {
        #pragma unroll
        for (int i = 0; i < 2; ++i) {
            int c = tid + i * 256;
            async_cp16(B + (n0 + (c >> 2)) * HID + k0 + (c & 3) * 8, Bs[b] + c * 8);
        }
    };
    auto stageA = [&](int k0, int b) {
        int h = k0 >> 9;
        float rv = rinv[h];
        int lk = (k0 & 511) + acol8;
        const unsigned short* ap = Opart + (h ? 3 * SH2 : 0) + (size_t)arow * 512 + lk;
        float s[8] = {0.f, 0.f, 0.f, 0.f, 0.f, 0.f, 0.f, 0.f};
        int nz = h ? 5 : 3;
        for (int z = 0; z < nz; ++z) {
            uint4 v = *(const uint4*)(ap + (size_t)z * SH2);
            unsigned short us[8];
            *(uint4*)us = v;
            #pragma unroll
            for (int e = 0; e < 8; ++e) s[e] += b2f(us[e]);
        }
        unsigned short o8[8];
        #pragma unroll
        for (int e = 0; e < 8; ++e) o8[e] = f2b(s[e] * rv);
        *(uint4*)(As[b] + tid * 8) = *(const uint4*)o8;
    };

    f32x4 zero = {0.f, 0.f, 0.f, 0.f};
    f32x4 acc[4][2];
    #pragma unroll
    for (int i = 0; i < 4; ++i)
        #pragma unroll
        for (int j = 0; j < 2; ++j) acc[i][j] = zero;

    stageB(0, 0);
    stageA(0, 0);
    for (int it = 0; it < HID / 32; ++it) {
        int b = it & 1;
        __syncthreads();
        if (it + 1 < HID / 32) {
            stageB((it + 1) * 32, b ^ 1);
            stageA((it + 1) * 32, b ^ 1);
        }
        bf16x8 af[4], bfr[2];
        #pragma unroll
        for (int i = 0; i < 4; ++i)
            af[i] = *(const bf16x8*)(As[b] + (i * 16 + l16) * 32 + quad * 8);
        #pragma unroll
        for (int j = 0; j < 2; ++j)
            bfr[j] = *(const bf16x8*)(Bs[b] + (wave * 32 + j * 16 + l16) * 32 + quad * 8);
        #pragma unroll
        for (int i = 0; i < 4; ++i)
            #pragma unroll
            for (int j = 0; j < 2; ++j)
                acc[i][j] = __builtin_amdgcn_mfma_f32_16x16x32_bf16(af[i], bfr[j], acc[i][j], 0, 0, 0);
    }

    #pragma unroll
    for (int i = 0; i < 4; ++i) {
        int rbase = m0 + i * 16 + quad * 4;
        #pragma unroll
        for (int j = 0; j < 2; ++j) {
            int col = n0 + wave * 32 + j * 16 + l16;
            #pragma unroll
            for (int r = 0; r < 4; ++r) {
                size_t o = (size_t)(rbase + r) * HID + col;
                Cf[o] = acc[i][j][r] + Xres[o];
            }
        }
    }
}

// ---------------- flash attention: 128 queries x one (head, key-split) ----------------
// R18 = R8 inner loop EXACTLY (proven 85us); only source pointers/strides changed:
// head-0: Kc [PADK][512] / Vtc [512][PADK]; head-1: Kb1 [S][512] / Vt1 [512][S].
__global__ __launch_bounds__(512, 2)
void k_flash(const unsigned short* __restrict__ Q,
             const unsigned short* __restrict__ Kb1,
             const unsigned short* __restrict__ Vt1,
             const unsigned short* __restrict__ Kc,
             const unsigned short* __restrict__ Vtc,
             const int* __restrict__ nactp,
             unsigned short* __restrict__ Opart,       // [8][S][512] per-head local cols
             float* __restrict__ Lbuf) {               // [8][S]
    __shared__ unsigned short Ks[2][32 * KS_STRIDE];
    __shared__ __bf16 Ps[2][128][40];
    int tid  = threadIdx.x;
    int wave = tid >> 6, lane = tid & 63;
    int quad = lane >> 4, l16 = lane & 15;
    int x = blockIdx.x, qtile = blockIdx.y;
    int head  = (x >= 3) ? 1 : 0;
    int split = head ? x - 3 : x;
    int nact  = nactp[0];

    int nit, base, vrs;
    const unsigned short *Ksrc, *Vsrc;
    if (head == 0) {
        nit  = (nact + 95) / 96;          // ceil(nact / (3 splits * 32))
        base = split * nit * 32;
        Ksrc = Kc;  Vsrc = Vtc; vrs = PADK;
    } else {
        base = split * CH1;
        nit  = min(CH1 >> 5, (S_LEN - base) >> 5);
        Ksrc = Kb1; Vsrc = Vt1; vrs = S_LEN;
    }

    // Q fragments (A-operand: A[m=lane&15][k=quad*8+j]), pinned in registers
    int qrow = qtile * 128 + wave * 16 + l16;
    const unsigned short* qp = Q + qrow * HID + head * HDIM;
    bf16x8 qf[16];
    #pragma unroll
    for (int t = 0; t < 16; ++t) qf[t] = *(const bf16x8*)(qp + t * 32 + quad * 8);

    float lsum[4];
    #pragma unroll
    for (int r = 0; r < 4; ++r) lsum[r] = 0.f;
    f32x4 zero = {0.f, 0.f, 0.f, 0.f};
    f32x4 oacc[8][4];
    #pragma unroll
    for (int mt = 0; mt < 8; ++mt)
        #pragma unroll
        for (int nt = 0; nt < 4; ++nt) oacc[mt][nt] = zero;

    const float scale = 0.044194173824159216f; // 1/sqrt(512)
    const unsigned short* vptr = Vsrc + (size_t)(wave * 64 + l16) * vrs + base + quad * 8;

    auto stageK = [&](int kt, int buf) {
        int kb = base + kt * 32;
        #pragma unroll
        for (int i = 0; i < 4; ++i) {
            int c = tid + i * 512;
            int row = c >> 6, col = (c & 63) * 8;   // per-wave: row uniform, col = lane*16B
            async_cp16(Ksrc + (size_t)(kb + row) * 512 + col, &Ks[buf][row * KS_STRIDE + col]);
        }
    };

    if (nit > 0) stageK(0, 0);

    bf16x8 vf[4];
    for (int it = 0; it < nit; ++it) {
        int cur = it & 1;
        __syncthreads();   // Ks[cur] DMA drained; Ps[cur] free; Ps[cur^1] written

        if (it + 1 < nit) stageK(it + 1, cur ^ 1);

        __builtin_amdgcn_s_setprio(1);
        if (it > 0) {
            #pragma unroll
            for (int mt = 0; mt < 8; ++mt) {
                bf16x8 pf = *(const bf16x8*)&Ps[cur ^ 1][mt * 16 + l16][quad * 8];
                #pragma unroll
                for (int nt = 0; nt < 4; ++nt)
                    oacc[mt][nt] = __builtin_amdgcn_mfma_f32_16x16x32_bf16(pf, vf[nt], oacc[mt][nt], 0, 0, 0);
            }
        }

        // V prefetch for THIS tile (16 VGPR carry, proven budget)
        #pragma unroll
        for (int nt = 0; nt < 4; ++nt)
            vf[nt] = *(const bf16x8*)(vptr + (size_t)nt * 16 * vrs + it * 32);

        // S = Q K^T
        f32x4 sacc[2];
        sacc[0] = zero; sacc[1] = zero;
        #pragma unroll
        for (int nt = 0; nt < 2; ++nt)
            #pragma unroll
            for (int t = 0; t < 16; ++t) {
                bf16x8 kf = *(const bf16x8*)&Ks[cur][(nt * 16 + l16) * KS_STRIDE + t * 32 + quad * 8];
                sacc[nt] = __builtin_amdgcn_mfma_f32_16x16x32_bf16(qf[t], kf, sacc[nt], 0, 0, 0);
            }
        __builtin_amdgcn_s_setprio(0);

        // validity: compacted head-0 keys need only the nact bound; head-1 all valid
        bool keep0 = true, keep1 = true;
        if (head == 0) {
            int kb = base + it * 32;
            keep0 = kb + l16 < nact;
            keep1 = kb + 16 + l16 < nact;
        }
        #pragma unroll
        for (int r = 0; r < 4; ++r) {
            float p0 = keep0 ? __expf(fminf(sacc[0][r] * scale, 30.f)) : 0.f;
            float p1 = keep1 ? __expf(fminf(sacc[1][r] * scale, 30.f)) : 0.f;
            lsum[r] += p0 + p1;
            Ps[cur][wave * 16 + quad * 4 + r][l16]      = (__bf16)p0;
            Ps[cur][wave * 16 + quad * 4 + r][16 + l16] = (__bf16)p1;
        }
    }

    // epilogue PV for the last tile
    if (nit > 0) {
        int lastb = (nit - 1) & 1;
        __syncthreads();
        #pragma unroll
        for (int mt = 0; mt < 8; ++mt) {
            bf16x8 pf = *(const bf16x8*)&Ps[lastb][mt * 16 + l16][quad * 8];
            #pragma unroll
            for (int nt = 0; nt < 4; ++nt)
                oacc[mt][nt] = __builtin_amdgcn_mfma_f32_16x16x32_bf16(pf, vf[nt], oacc[mt][nt], 0, 0, 0);
        }
    }

    // l-reduction across the 16 lanes of this quad
    #pragma unroll
    for (int r = 0; r < 4; ++r) {
        float s = lsum[r];
        #pragma unroll
        for (int off = 1; off < 16; off <<= 1)
            s += __shfl_xor(s, off, 64);
        lsum[r] = s;
    }
    int slot = head ? 3 + split : split;
    int lrow = qtile * 128 + wave * 16 + quad * 4;
    if (l16 == 0) {
        #pragma unroll
        for (int r = 0; r < 4; ++r)
            Lbuf[slot * S_LEN + lrow + r] = lsum[r];
    }
    // O epilogue: per-head local cols (512-wide)
    unsigned short* op = Opart + (size_t)slot * S_LEN * 512;
    #pragma unroll
    for (int mt = 0; mt < 8; ++mt)
        #pragma unroll
        for (int nt = 0; nt < 4; ++nt)
            #pragma unroll
            for (int r = 0; r < 4; ++r)
                op[(qtile * 128 + mt * 16 + quad * 4 + r) * 512 +
                   wave * 64 + nt * 16 + l16] = f2b(oacc[mt][nt][r]);
}

// ---------------- per-row LayerNorm over H=1024 (fp32 in, fp32 out) ----------------
__global__ __launch_bounds__(256)
void k_ln(const float* __restrict__ res,
          const float* __restrict__ w,
          const float* __restrict__ b,
          float* __restrict__ out) {
    __shared__ float red[8];
    int s = blockIdx.x, tid = threadIdx.x;
    const float* row = res + s * HID;
    float x[4], s1 = 0.f, s2 = 0.f;
    #pragma unroll
    for (int i = 0; i < 4; ++i) {
        x[i] = row[tid + i * 256];
        s1 += x[i]; s2 += x[i] * x[i];
    }
    #pragma unroll
    for (int off = 1; off < 64; off <<= 1) {
        s1 += __shfl_xor(s1, off, 64);
        s2 += __shfl_xor(s2, off, 64);
    }
    int wave = tid >> 6;
    if ((tid & 63) == 0) { red[wave] = s1; red[4 + wave] = s2; }
    __syncthreads();
    s1 = red[0] + red[1] + red[2] + red[3];
    s2 = red[4] + red[5] + red[6] + red[7];
    float mu   = s1 * (1.f / HID);
    float var  = s2 * (1.f / HID) - mu * mu;
    float rstd = rsqrtf(var + LN_EPS);
    #pragma unroll
    for (int i = 0; i < 4; ++i) {
        int col = tid + i * 256;
        out[s * HID + col] = (x[i] - mu) * rstd * w[col] + b[col];
    }
}

extern "C" void kernel_launch(void* const* d_in, const int* in_sizes, int n_in,
                              void* d_out, int out_size, void* d_ws, size_t ws_size,
                              hipStream_t stream) {
    const float* X   = (const float*)d_in[0];
    const float* sd  = (const float*)d_in[1];
    const int*   msk = (const int*)d_in[2];
    const float* Wq  = (const float*)d_in[3];
    const float* Wk  = (const float*)d_in[4];
    const float* Wv  = (const float*)d_in[5];
    const float* Wo  = (const float*)d_in[6];
    const float* Wsp = (const float*)d_in[7];
    const float* bsp = (const float*)d_in[8];
    const float* lw  = (const float*)d_in[9];
    const float* lb  = (const float*)d_in[10];
    float* out = (float*)d_out;

    // Workspace map — 89MB proven envelope (R7 lesson). Live ranges:
    //  Xb/kvin (1..17M): written by k_kvin, read by k_gemms, dead after.
    //  Qb (17..25M), Kb1 (25..29M), Vt1 (29..33M): written by k_gemms, read by flash, dead.
    //  Kc (33..37.2M), Vtc (37.25..41.4M): written by k_gemms, read by flash.
    //  resf (17..33M) overlays dead Qb/Kb1/Vt1: written by gemm_o AFTER flash.
    char* ws = (char*)d_ws;
    const size_t MB = 1ull << 20;
    float*          semb  = (float*)(ws);                     // 4 KB @0
    int*            cidx  = (int*)(ws + (16 << 10));          // 16.9 KB @16K (PADK ints)
    int*            nactp = (int*)(ws + (48 << 10));          // 4 B @48K
    float*          Lbuf  = (float*)(ws + (1ull << 16));      // 128 KB @64K (8 slots x S)
    unsigned short* Xb    = (unsigned short*)(ws + 1 * MB);   // 8 MB
    unsigned short* kvin  = (unsigned short*)(ws + 9 * MB);   // 8 MB
    unsigned short* Qb    = (unsigned short*)(ws + 17 * MB);  // 8 MB
    unsigned short* Kb1   = (unsigned short*)(ws + 25 * MB);  // 4 MB [S][512]
    unsigned short* Vt1   = (unsigned short*)(ws + 29 * MB);  // 4 MB [512][S]
    unsigned short* Kc    = (unsigned short*)(ws + 33 * MB);  // 4.125 MB [PADK][512]
    unsigned short* Vtc   = (unsigned short*)(ws + 37 * MB + (256 << 10)); // 4.125 MB
    unsigned short* Wqb   = (unsigned short*)(ws + 49 * MB);  // 2 MB
    unsigned short* Wkb   = (unsigned short*)(ws + 51 * MB);  // 2 MB
    unsigned short* Wvb   = (unsigned short*)(ws + 53 * MB);  // 2 MB
    unsigned short* Wob   = (unsigned short*)(ws + 55 * MB);  // 2 MB
    float*          resf  = (float*)(ws + 17 * MB);           // 16 MB over dead Qb/Kb1/Vt1
    unsigned short* Opart = (unsigned short*)(ws + 57 * MB);  // 32 MB [8][S][512] -> 89 MB

    const int SH = S_LEN * HID;   // 4M
    const int WW = HID * HID;     // 1M

    // weights->bf16 (z=0..3) + semb (z=4) + mask compaction (z=5)
    k_cvt4s<<<dim3(WW / 8 / 256, 6), dim3(256), 0, stream>>>(
        Wq, Wk, Wv, Wo, Wqb, Wkb, Wvb, Wob, Wsp, sd, bsp, semb, msk, cidx, nactp);

    k_kvin<<<dim3(SH / 8 / 256), dim3(256), 0, stream>>>(X, semb, Xb, kvin);

    // all projections incl. directly-compacted head-0 K/V: 776 blocks
    k_gemms<<<dim3(776), dim3(256), 0, stream>>>(
        Xb, kvin, Wqb, Wkb, Wvb, cidx, Qb, Kb1, Vt1, Kc, Vtc);

    // asymmetric splits: x 0..2 = head0 (compacted), x 3..7 = head1; y = qtile (32)
    k_flash<<<dim3(8, S_LEN / 128), dim3(512), 0, stream>>>(
        Qb, Kb1, Vt1, Kc, Vtc, nactp, Opart, Lbuf);

    // out-projection with fused split-combine + normalize + residual
    k_gemm_o<<<dim3(512), dim3(256), 0, stream>>>(Opart, Lbuf, Wob, resf, X);
    k_ln<<<dim3(S_LEN), dim3(256), 0, stream>>>(resf, lw, lb, out);
}